// Round 9
// baseline (172.053 us; speedup 1.0000x reference)
//
#include <hip/hip_runtime.h>
#include <hip/hip_bf16.h>

#define NN 8192
#define LOG2E 1.44269504088896f
#define S_SPLIT 8
#define JC 1024
#define NT 32

typedef __attribute__((ext_vector_type(8))) short short8;
typedef __attribute__((ext_vector_type(4))) float f32x4;
typedef __attribute__((ext_vector_type(4))) int int4v;

static __device__ __forceinline__ float bf2f(unsigned short u) {
    union { unsigned int i; float f; } v; v.i = ((unsigned int)u) << 16; return v.f;
}
static __device__ __forceinline__ unsigned short f2bf(float f) {
    union { float f; unsigned int i; } v; v.f = f;
    unsigned int lsb = (v.i >> 16) & 1u;
    v.i += 0x7fffu + lsb;
    return (unsigned short)(v.i >> 16);
}
static __device__ __forceinline__ unsigned int cvtpk(float lo, float hi) {
    unsigned int r;
    asm("v_cvt_pk_bf16_f32 %0, %1, %2" : "=v"(r) : "v"(lo), "v"(hi));
    return r;
}
static __device__ __forceinline__ float fexp2(float x) { return __builtin_amdgcn_exp2f(x); }

static __device__ __forceinline__ void cvt8(const float* __restrict__ p, short8& hi, short8& lo) {
    float4 u = *(const float4*)p;
    float4 v = *(const float4*)(p + 4);
    float f[8] = {u.x, u.y, u.z, u.w, v.x, v.y, v.z, v.w};
#pragma unroll
    for (int j = 0; j < 8; ++j) {
        unsigned short hb = f2bf(f[j]);
        hi[j] = (short)hb;
        lo[j] = (short)f2bf(f[j] - bf2f(hb));
    }
}

// ---- prep: v1/v2 (W^T a vectors), split over 16 blocks then reduced ----
__global__ void prep_partial(const float* __restrict__ W1, const float* __restrict__ W2,
                             const float* __restrict__ a,
                             float* __restrict__ v1p, float* __restrict__ v2p) {
    int b = blockIdx.x;
    int t = threadIdx.x;
    int hh = t >> 8, k = t & 255;
    int c0 = (b & 7) * 16;
    const float* W = (b < 8) ? W1 : W2;
    int aoff = (b < 8) ? 0 : 128;
    float acc = 0.f;
    for (int c = c0; c < c0 + 16; ++c)
        acc += W[(size_t)(hh * 128 + c) * 256 + k] * a[hh * 256 + aoff + c];
    ((b < 8) ? v1p : v2p)[(b & 7) * 512 + t] = acc;
}

__global__ void prep_reduce(const float* __restrict__ b1, const float* __restrict__ b2,
                            const float* __restrict__ a,
                            const float* __restrict__ v1p, const float* __restrict__ v2p,
                            float* __restrict__ v1, float* __restrict__ v2, float* __restrict__ bd) {
    int t = threadIdx.x;
    float a1 = 0.f, a2 = 0.f;
    for (int b = 0; b < 8; ++b) { a1 += v1p[b * 512 + t]; a2 += v2p[b * 512 + t]; }
    v1[t] = a1;
    v2[t] = a2;
    int g = t >> 7;
    int hh = g >> 1, which = g & 1, c = t & 127;
    float prod = which ? b2[hh * 128 + c] * a[hh * 256 + 128 + c]
                       : b1[hh * 128 + c] * a[hh * 256 + c];
#pragma unroll
    for (int off = 1; off < 64; off <<= 1) prod += __shfl_xor(prod, off);
    __shared__ float ws[8];
    if ((t & 63) == 0) ws[t >> 6] = prod;
    __syncthreads();
    if (t < 4) bd[t] = ws[2 * t] + ws[2 * t + 1];
}

// s1[n][h] interleaved; s2 per-head planes s2h[h][n]. Both pre-scaled by log2(e).
__global__ __launch_bounds__(256) void s_kernel(const float* __restrict__ hmat,
                         const float* __restrict__ v1, const float* __restrict__ v2,
                         const float* __restrict__ bd,
                         float* __restrict__ s1o, float* __restrict__ s2o) {
    int w = threadIdx.x >> 6, l = threadIdx.x & 63;
    int n = blockIdx.x * 4 + w;
    float4 hv  = *(const float4*)(hmat + (size_t)n * 256 + l * 4);
    float4 va0 = *(const float4*)(v1 + l * 4);
    float4 va1 = *(const float4*)(v1 + 256 + l * 4);
    float4 vb0 = *(const float4*)(v2 + l * 4);
    float4 vb1 = *(const float4*)(v2 + 256 + l * 4);
    float s10 = hv.x*va0.x + hv.y*va0.y + hv.z*va0.z + hv.w*va0.w;
    float s11 = hv.x*va1.x + hv.y*va1.y + hv.z*va1.z + hv.w*va1.w;
    float s20 = hv.x*vb0.x + hv.y*vb0.y + hv.z*vb0.z + hv.w*vb0.w;
    float s21 = hv.x*vb1.x + hv.y*vb1.y + hv.z*vb1.z + hv.w*vb1.w;
#pragma unroll
    for (int off = 1; off < 64; off <<= 1) {
        s10 += __shfl_xor(s10, off);
        s11 += __shfl_xor(s11, off);
        s20 += __shfl_xor(s20, off);
        s21 += __shfl_xor(s21, off);
    }
    if (l == 0) {
        s1o[n*2 + 0] = (s10 + bd[0]) * LOG2E;
        s1o[n*2 + 1] = (s11 + bd[2]) * LOG2E;
        s2o[n]       = (s20 + bd[1]) * LOG2E;
        s2o[NN + n]  = (s21 + bd[3]) * LOG2E;
    }
}

// W3 -> bf16 hi/lo planes (once).
__global__ void wcvt_kernel(const float* __restrict__ W3,
                            unsigned short* __restrict__ w3hi, unsigned short* __restrict__ w3lo) {
    int i = blockIdx.x * 256 + threadIdx.x;
    float f = W3[i];
    unsigned short hb = f2bf(f);
    w3hi[i] = hb;
    w3lo[i] = f2bf(f - bf2f(hb));
}

// W3h in MFMA-fragment-major layout (w3b), split-bf16 3-MFMA.
__global__ __launch_bounds__(256) void w3_kernel(const float* __restrict__ hmat,
                                                 const unsigned short* __restrict__ w3hi,
                                                 const unsigned short* __restrict__ w3lo,
                                                 const float* __restrict__ b3,
                                                 unsigned short* __restrict__ w3b) {
    int tid = threadIdx.x;
    int w = tid >> 6, l = tid & 63;
    int m = l & 15, kq = l >> 4;
    int n0 = (blockIdx.x * 2 + (w & 1)) * 16;
    int c0 = (w >> 1) * 8;
    f32x4 acc[8];
#pragma unroll
    for (int ct = 0; ct < 8; ++ct) acc[ct] = (f32x4){0.f, 0.f, 0.f, 0.f};
    for (int k0 = 0; k0 < 256; k0 += 32) {
        short8 ahi, alo;
        cvt8(hmat + (size_t)(n0 + m) * 256 + k0 + kq * 8, ahi, alo);
#pragma unroll
        for (int ct = 0; ct < 8; ++ct) {
            int c = (c0 + ct) * 16 + m;
            short8 bhi = *(const short8*)&w3hi[(size_t)c * 256 + k0 + kq * 8];
            short8 blo = *(const short8*)&w3lo[(size_t)c * 256 + k0 + kq * 8];
            acc[ct] = __builtin_amdgcn_mfma_f32_16x16x32_bf16(ahi, bhi, acc[ct], 0, 0, 0);
            acc[ct] = __builtin_amdgcn_mfma_f32_16x16x32_bf16(alo, bhi, acc[ct], 0, 0, 0);
            acc[ct] = __builtin_amdgcn_mfma_f32_16x16x32_bf16(ahi, blo, acc[ct], 0, 0, 0);
        }
    }
#pragma unroll
    for (int ct = 0; ct < 8; ++ct) {
        int c = (c0 + ct) * 16 + m;
        float bias = b3[c];
#pragma unroll
        for (int e = 0; e < 4; ++e) {
            int n = n0 + kq * 4 + e;
            size_t idx = ((size_t)(n >> 5) * 16 + (c >> 4)) * 512 + (size_t)((((n >> 3) & 3) * 16 + m) * 8 + (n & 7));
            w3b[idx] = f2bf(acc[ct][e] + bias);
        }
    }
}

// ---- main fused attention ----
// 512 thr = 8 waves; block = 64 rows x 256 cols (wave: rg=wv&1 row-half, cg=wv>>1 col-quarter,
// head hw=cg>>1). Raw adj read in-loop (nontemporal int4, depth-2 register prefetch) — the
// one-time 256 MB HBM stream rides under compute; no pack pass. P computed cooperatively once
// (thread (r,oct): row r, 4 j's, both heads) into double-buffered swizzled Pt => ONE barrier
// per iter. B-frags direct from fragment-major w3b (L2). Denominator via ones-B-frag MFMA.
__global__ __launch_bounds__(512, 4) void attn_fused(
        const int* __restrict__ adj, const float* __restrict__ s1a,
        const float* __restrict__ s2h, const unsigned short* __restrict__ w3b,
        unsigned short* __restrict__ pacc, float* __restrict__ pden)
{
    __shared__ unsigned short Pt[2][2][64][32];  // [buf][head][row][j] 16 KB, swizzled granules
    __shared__ float s2t[2][JC];                 // 8 KB

    const int tid = threadIdx.x;
    const int wv = tid >> 6, ln = tid & 63;
    const int m = ln & 15, kq = ln >> 4;
    const int rg = wv & 1, cg = wv >> 1;
    const int hw = cg >> 1;
    const int r = tid >> 3, oct = tid & 7;
    const int i0 = blockIdx.x * 64;
    const int sidx = blockIdx.y;
    const int j0 = sidx * JC;
    const int sw = kq ^ ((m >> 1) & 3);

    const float s1r0 = s1a[(i0 + r) * 2 + 0];
    const float s1r1 = s1a[(i0 + r) * 2 + 1];
    const int* adjRow = adj + (size_t)(i0 + r) * NN + j0 + oct * 4;
    // swizzled Pt write ptr (buf 0, head 0); head stride 2048 shorts, buf stride 4096
    unsigned short* ptw = &Pt[0][0][0][0] + r * 32 + ((((oct >> 1) ^ ((r >> 1) & 3)) << 3) | ((oct & 1) << 2));
    // swizzled Pt read base (buf 0): row rg*32+m, granule sw; second frag at +512
    const unsigned short* pta = &Pt[0][0][0][0] + (size_t)hw * 2048 + (rg * 32 + m) * 32 + (sw << 3);
    const unsigned short* w3p = w3b + ((size_t)(j0 >> 5) * 16 + cg * 4) * 512 + ln * 8;

    f32x4 acc[2][4];
    f32x4 accd[2];
#pragma unroll
    for (int rt = 0; rt < 2; ++rt) {
        accd[rt] = (f32x4){0.f, 0.f, 0.f, 0.f};
#pragma unroll
        for (int f = 0; f < 4; ++f) acc[rt][f] = (f32x4){0.f, 0.f, 0.f, 0.f};
    }
    short8 ones;
#pragma unroll
    for (int e = 0; e < 8; ++e) ones[e] = (short)0x3F80;

    // prologue: stage s2 planes; adj depth-2 prefetch
    for (int x = tid; x < 2 * JC; x += 512) {
        int h = x >> 10, j = x & (JC - 1);
        s2t[h][j] = s2h[(size_t)h * NN + j0 + j];
    }
    int4v aCur = __builtin_nontemporal_load((const int4v*)(adjRow));
    int4v aNxt = __builtin_nontemporal_load((const int4v*)(adjRow + 32));
    __syncthreads();

    for (int t = 0; t < NT; ++t) {
        const int buf = t & 1;
        // B(t) loads (L2-resident; consumed after the barrier)
        const unsigned short* bp = w3p + (size_t)t * 8192;
        short8 bf0 = *(const short8*)(bp);
        short8 bf1 = *(const short8*)(bp + 512);
        short8 bf2 = *(const short8*)(bp + 1024);
        short8 bf3 = *(const short8*)(bp + 1536);
        // adj prefetch t+2 (HBM, nontemporal — don't pollute L2)
        int tn2 = (t + 2 < NT) ? t + 2 : NT - 1;
        int4v aNew = __builtin_nontemporal_load((const int4v*)(adjRow + tn2 * 32));
        // ---- P-gen(t) -> Pt[buf] ----
        {
            float4 sv0 = *(const float4*)&s2t[0][t * 32 + oct * 4];
            float4 sv1 = *(const float4*)&s2t[1][t * 32 + oct * 4];
            float x0, q0, q1, q2, q3, u0, u1, u2, u3;
            x0 = s1r0 + sv0.x; x0 = fmaxf(x0, 0.2f * x0); q0 = aCur.x ? fexp2(x0) : 0.f;
            x0 = s1r0 + sv0.y; x0 = fmaxf(x0, 0.2f * x0); q1 = aCur.y ? fexp2(x0) : 0.f;
            x0 = s1r0 + sv0.z; x0 = fmaxf(x0, 0.2f * x0); q2 = aCur.z ? fexp2(x0) : 0.f;
            x0 = s1r0 + sv0.w; x0 = fmaxf(x0, 0.2f * x0); q3 = aCur.w ? fexp2(x0) : 0.f;
            x0 = s1r1 + sv1.x; x0 = fmaxf(x0, 0.2f * x0); u0 = aCur.x ? fexp2(x0) : 0.f;
            x0 = s1r1 + sv1.y; x0 = fmaxf(x0, 0.2f * x0); u1 = aCur.y ? fexp2(x0) : 0.f;
            x0 = s1r1 + sv1.z; x0 = fmaxf(x0, 0.2f * x0); u2 = aCur.z ? fexp2(x0) : 0.f;
            x0 = s1r1 + sv1.w; x0 = fmaxf(x0, 0.2f * x0); u3 = aCur.w ? fexp2(x0) : 0.f;
            uint2 w0 = {cvtpk(q0, q1), cvtpk(q2, q3)};
            uint2 w1 = {cvtpk(u0, u1), cvtpk(u2, u3)};
            unsigned short* pw = ptw + buf * 4096;
            *(uint2*)pw = w0;
            *(uint2*)(pw + 2048) = w1;
        }
        asm volatile("s_waitcnt lgkmcnt(0)" ::: "memory");
        __builtin_amdgcn_sched_barrier(0);
        __builtin_amdgcn_s_barrier();
        asm volatile("" ::: "memory");
        // ---- MFMA(t): A-frags from Pt[buf] (swizzled), B in regs ----
        {
            const unsigned short* pa = pta + buf * 4096;
            short8 a0 = *(const short8*)pa;
            short8 a1 = *(const short8*)(pa + 512);
            __builtin_amdgcn_s_setprio(1);
            acc[0][0] = __builtin_amdgcn_mfma_f32_16x16x32_bf16(a0, bf0, acc[0][0], 0, 0, 0);
            acc[1][0] = __builtin_amdgcn_mfma_f32_16x16x32_bf16(a1, bf0, acc[1][0], 0, 0, 0);
            acc[0][1] = __builtin_amdgcn_mfma_f32_16x16x32_bf16(a0, bf1, acc[0][1], 0, 0, 0);
            acc[1][1] = __builtin_amdgcn_mfma_f32_16x16x32_bf16(a1, bf1, acc[1][1], 0, 0, 0);
            acc[0][2] = __builtin_amdgcn_mfma_f32_16x16x32_bf16(a0, bf2, acc[0][2], 0, 0, 0);
            acc[1][2] = __builtin_amdgcn_mfma_f32_16x16x32_bf16(a1, bf2, acc[1][2], 0, 0, 0);
            acc[0][3] = __builtin_amdgcn_mfma_f32_16x16x32_bf16(a0, bf3, acc[0][3], 0, 0, 0);
            acc[1][3] = __builtin_amdgcn_mfma_f32_16x16x32_bf16(a1, bf3, acc[1][3], 0, 0, 0);
            if ((cg & 1) == 0) {
                accd[0] = __builtin_amdgcn_mfma_f32_16x16x32_bf16(a0, ones, accd[0], 0, 0, 0);
                accd[1] = __builtin_amdgcn_mfma_f32_16x16x32_bf16(a1, ones, accd[1], 0, 0, 0);
            }
            __builtin_amdgcn_s_setprio(0);
        }
        aCur = aNxt; aNxt = aNew;
    }

    // pden from ones-MFMA accumulators (waves cg=0 head0, cg=2 head1; all m lanes equal)
    if ((cg & 1) == 0 && m == 0) {
#pragma unroll
        for (int rt = 0; rt < 2; ++rt)
#pragma unroll
            for (int e = 0; e < 4; ++e) {
                int row = i0 + rg * 32 + rt * 16 + kq * 4 + e;
                pden[((size_t)sidx * NN + row) * 2 + hw] = accd[rt][e];
            }
    }
    size_t pb_ = (size_t)sidx * NN * 256;
#pragma unroll
    for (int rt = 0; rt < 2; ++rt)
#pragma unroll
        for (int e = 0; e < 4; ++e) {
            int row = i0 + rg * 32 + rt * 16 + kq * 4 + e;
#pragma unroll
            for (int f = 0; f < 4; ++f) {
                int col = cg * 64 + f * 16 + m;
                __builtin_nontemporal_store(f2bf(acc[rt][f][e]), &pacc[pb_ + (size_t)row * 256 + col]);
            }
        }
}

// combine: 8 outputs per thread
__global__ void combine_kernel(const unsigned short* __restrict__ pacc, const float* __restrict__ pden,
                               float* __restrict__ out) {
    size_t idx = ((size_t)blockIdx.x * 256 + threadIdx.x) * 8;
    int i = (int)(idx >> 8);
    int c = (int)(idx & 255);
    int hh = c >> 7;
    float acc[8];
#pragma unroll
    for (int e = 0; e < 8; ++e) acc[e] = 0.f;
    float den = 0.f;
    for (int s = 0; s < S_SPLIT; ++s) {
        uint4 v = *(const uint4*)&pacc[(size_t)s * NN * 256 + idx];
        unsigned int uu[4] = {v.x, v.y, v.z, v.w};
#pragma unroll
        for (int q = 0; q < 4; ++q) {
            acc[2*q]   += bf2f((unsigned short)(uu[q] & 0xffff));
            acc[2*q+1] += bf2f((unsigned short)(uu[q] >> 16));
        }
        den += pden[((size_t)s * NN + i) * 2 + hh];
    }
    float r = 1.f / den;
    float4 o0 = {acc[0]*r, acc[1]*r, acc[2]*r, acc[3]*r};
    float4 o1 = {acc[4]*r, acc[5]*r, acc[6]*r, acc[7]*r};
    *(float4*)&out[idx] = o0;
    *(float4*)&out[idx + 4] = o1;
}

extern "C" void kernel_launch(void* const* d_in, const int* in_sizes, int n_in,
                              void* d_out, int out_size, void* d_ws, size_t ws_size,
                              hipStream_t stream) {
    const float* hmat = (const float*)d_in[0];
    const int*   adj  = (const int*)d_in[1];
    const float* W1   = (const float*)d_in[2];
    const float* b1   = (const float*)d_in[3];
    const float* W2   = (const float*)d_in[4];
    const float* b2   = (const float*)d_in[5];
    const float* W3   = (const float*)d_in[6];
    const float* b3   = (const float*)d_in[7];
    const float* a    = (const float*)d_in[8];
    float* out = (float*)d_out;

    char* p = (char*)d_ws;
    float* v1   = (float*)p; p += 2048;
    float* v2   = (float*)p; p += 2048;
    float* bd   = (float*)p; p += 256;
    float* s1   = (float*)p; p += (size_t)NN * 2 * sizeof(float);
    float* s2h  = (float*)p; p += (size_t)NN * 2 * sizeof(float);
    float* v1p  = (float*)p; p += 8 * 512 * sizeof(float);
    float* v2p  = (float*)p; p += 8 * 512 * sizeof(float);
    unsigned short* w3hi = (unsigned short*)p; p += 65536 * 2;
    unsigned short* w3lo = (unsigned short*)p; p += 65536 * 2;
    unsigned short* w3b  = (unsigned short*)p; p += (size_t)NN * 256 * 2;
    float* pden = (float*)p; p += (size_t)S_SPLIT * NN * 2 * sizeof(float);
    unsigned short* pacc = (unsigned short*)p;

    prep_partial<<<16, 512, 0, stream>>>(W1, W2, a, v1p, v2p);
    prep_reduce<<<1, 512, 0, stream>>>(b1, b2, a, v1p, v2p, v1, v2, bd);
    s_kernel<<<NN / 4, 256, 0, stream>>>(hmat, v1, v2, bd, s1, s2h);
    wcvt_kernel<<<256, 256, 0, stream>>>(W3, w3hi, w3lo);
    w3_kernel<<<256, 256, 0, stream>>>(hmat, w3hi, w3lo, b3, w3b);
    attn_fused<<<dim3(NN / 64, S_SPLIT), 512, 0, stream>>>(adj, s1, s2h, w3b, pacc, pden);
    combine_kernel<<<(NN * 256) / (256 * 8), 256, 0, stream>>>(pacc, pden, out);
}

// Round 10
// 153.716 us; speedup vs baseline: 1.1193x; 1.1193x over previous
//
#include <hip/hip_runtime.h>
#include <hip/hip_bf16.h>

#define NN 8192
#define LOG2E 1.44269504088896f
#define S_SPLIT 8
#define JC 1024
#define NT 32

typedef __attribute__((ext_vector_type(8))) short short8;
typedef __attribute__((ext_vector_type(4))) float f32x4;

static __device__ __forceinline__ float bf2f(unsigned short u) {
    union { unsigned int i; float f; } v; v.i = ((unsigned int)u) << 16; return v.f;
}
static __device__ __forceinline__ unsigned short f2bf(float f) {
    union { float f; unsigned int i; } v; v.f = f;
    unsigned int lsb = (v.i >> 16) & 1u;
    v.i += 0x7fffu + lsb;
    return (unsigned short)(v.i >> 16);
}
static __device__ __forceinline__ unsigned int cvtpk(float lo, float hi) {
    unsigned int r;
    asm("v_cvt_pk_bf16_f32 %0, %1, %2" : "=v"(r) : "v"(lo), "v"(hi));
    return r;
}
static __device__ __forceinline__ float fexp2(float x) { return __builtin_amdgcn_exp2f(x); }

static __device__ __forceinline__ void cvt8(const float* __restrict__ p, short8& hi, short8& lo) {
    float4 u = *(const float4*)p;
    float4 v = *(const float4*)(p + 4);
    float f[8] = {u.x, u.y, u.z, u.w, v.x, v.y, v.z, v.w};
#pragma unroll
    for (int j = 0; j < 8; ++j) {
        unsigned short hb = f2bf(f[j]);
        hi[j] = (short)hb;
        lo[j] = (short)f2bf(f[j] - bf2f(hb));
    }
}

// ---- pack adj (256 MB int32 0/1) -> bitmask (8 MB). Pure streaming pass. ----
__global__ __launch_bounds__(256) void pack_kernel(const int* __restrict__ adj,
                                                   unsigned int* __restrict__ abits) {
    int w = blockIdx.x * 256 + threadIdx.x;
    const int* src = adj + (size_t)w * 32;
    unsigned int bits = 0;
#pragma unroll
    for (int k = 0; k < 8; ++k) {
        int4 v = *(const int4*)(src + k * 4);
        bits |= (unsigned int)(v.x & 1) << (k * 4 + 0);
        bits |= (unsigned int)(v.y & 1) << (k * 4 + 1);
        bits |= (unsigned int)(v.z & 1) << (k * 4 + 2);
        bits |= (unsigned int)(v.w & 1) << (k * 4 + 3);
    }
    abits[w] = bits;
}

// ---- prep: v1/v2 (W^T a vectors), split over 16 blocks then reduced ----
__global__ void prep_partial(const float* __restrict__ W1, const float* __restrict__ W2,
                             const float* __restrict__ a,
                             float* __restrict__ v1p, float* __restrict__ v2p) {
    int b = blockIdx.x;
    int t = threadIdx.x;
    int hh = t >> 8, k = t & 255;
    int c0 = (b & 7) * 16;
    const float* W = (b < 8) ? W1 : W2;
    int aoff = (b < 8) ? 0 : 128;
    float acc = 0.f;
    for (int c = c0; c < c0 + 16; ++c)
        acc += W[(size_t)(hh * 128 + c) * 256 + k] * a[hh * 256 + aoff + c];
    ((b < 8) ? v1p : v2p)[(b & 7) * 512 + t] = acc;
}

__global__ void prep_reduce(const float* __restrict__ b1, const float* __restrict__ b2,
                            const float* __restrict__ a,
                            const float* __restrict__ v1p, const float* __restrict__ v2p,
                            float* __restrict__ v1, float* __restrict__ v2, float* __restrict__ bd) {
    int t = threadIdx.x;
    float a1 = 0.f, a2 = 0.f;
    for (int b = 0; b < 8; ++b) { a1 += v1p[b * 512 + t]; a2 += v2p[b * 512 + t]; }
    v1[t] = a1;
    v2[t] = a2;
    int g = t >> 7;
    int hh = g >> 1, which = g & 1, c = t & 127;
    float prod = which ? b2[hh * 128 + c] * a[hh * 256 + 128 + c]
                       : b1[hh * 128 + c] * a[hh * 256 + c];
#pragma unroll
    for (int off = 1; off < 64; off <<= 1) prod += __shfl_xor(prod, off);
    __shared__ float ws[8];
    if ((t & 63) == 0) ws[t >> 6] = prod;
    __syncthreads();
    if (t < 4) bd[t] = ws[2 * t] + ws[2 * t + 1];
}

// s1[n][h] interleaved; s2 per-head planes s2h[h][n]. Both pre-scaled by log2(e).
__global__ __launch_bounds__(256) void s_kernel(const float* __restrict__ hmat,
                         const float* __restrict__ v1, const float* __restrict__ v2,
                         const float* __restrict__ bd,
                         float* __restrict__ s1o, float* __restrict__ s2o) {
    int w = threadIdx.x >> 6, l = threadIdx.x & 63;
    int n = blockIdx.x * 4 + w;
    float4 hv  = *(const float4*)(hmat + (size_t)n * 256 + l * 4);
    float4 va0 = *(const float4*)(v1 + l * 4);
    float4 va1 = *(const float4*)(v1 + 256 + l * 4);
    float4 vb0 = *(const float4*)(v2 + l * 4);
    float4 vb1 = *(const float4*)(v2 + 256 + l * 4);
    float s10 = hv.x*va0.x + hv.y*va0.y + hv.z*va0.z + hv.w*va0.w;
    float s11 = hv.x*va1.x + hv.y*va1.y + hv.z*va1.z + hv.w*va1.w;
    float s20 = hv.x*vb0.x + hv.y*vb0.y + hv.z*vb0.z + hv.w*vb0.w;
    float s21 = hv.x*vb1.x + hv.y*vb1.y + hv.z*vb1.z + hv.w*vb1.w;
#pragma unroll
    for (int off = 1; off < 64; off <<= 1) {
        s10 += __shfl_xor(s10, off);
        s11 += __shfl_xor(s11, off);
        s20 += __shfl_xor(s20, off);
        s21 += __shfl_xor(s21, off);
    }
    if (l == 0) {
        s1o[n*2 + 0] = (s10 + bd[0]) * LOG2E;
        s1o[n*2 + 1] = (s11 + bd[2]) * LOG2E;
        s2o[n]       = (s20 + bd[1]) * LOG2E;
        s2o[NN + n]  = (s21 + bd[3]) * LOG2E;
    }
}

// W3 -> bf16 hi/lo planes (once).
__global__ void wcvt_kernel(const float* __restrict__ W3,
                            unsigned short* __restrict__ w3hi, unsigned short* __restrict__ w3lo) {
    int i = blockIdx.x * 256 + threadIdx.x;
    float f = W3[i];
    unsigned short hb = f2bf(f);
    w3hi[i] = hb;
    w3lo[i] = f2bf(f - bf2f(hb));
}

// W3h in MFMA-fragment-major layout (w3b), split-bf16 3-MFMA.
__global__ __launch_bounds__(256) void w3_kernel(const float* __restrict__ hmat,
                                                 const unsigned short* __restrict__ w3hi,
                                                 const unsigned short* __restrict__ w3lo,
                                                 const float* __restrict__ b3,
                                                 unsigned short* __restrict__ w3b) {
    int tid = threadIdx.x;
    int w = tid >> 6, l = tid & 63;
    int m = l & 15, kq = l >> 4;
    int n0 = (blockIdx.x * 2 + (w & 1)) * 16;
    int c0 = (w >> 1) * 8;
    f32x4 acc[8];
#pragma unroll
    for (int ct = 0; ct < 8; ++ct) acc[ct] = (f32x4){0.f, 0.f, 0.f, 0.f};
    for (int k0 = 0; k0 < 256; k0 += 32) {
        short8 ahi, alo;
        cvt8(hmat + (size_t)(n0 + m) * 256 + k0 + kq * 8, ahi, alo);
#pragma unroll
        for (int ct = 0; ct < 8; ++ct) {
            int c = (c0 + ct) * 16 + m;
            short8 bhi = *(const short8*)&w3hi[(size_t)c * 256 + k0 + kq * 8];
            short8 blo = *(const short8*)&w3lo[(size_t)c * 256 + k0 + kq * 8];
            acc[ct] = __builtin_amdgcn_mfma_f32_16x16x32_bf16(ahi, bhi, acc[ct], 0, 0, 0);
            acc[ct] = __builtin_amdgcn_mfma_f32_16x16x32_bf16(alo, bhi, acc[ct], 0, 0, 0);
            acc[ct] = __builtin_amdgcn_mfma_f32_16x16x32_bf16(ahi, blo, acc[ct], 0, 0, 0);
        }
    }
#pragma unroll
    for (int ct = 0; ct < 8; ++ct) {
        int c = (c0 + ct) * 16 + m;
        float bias = b3[c];
#pragma unroll
        for (int e = 0; e < 4; ++e) {
            int n = n0 + kq * 4 + e;
            size_t idx = ((size_t)(n >> 5) * 16 + (c >> 4)) * 512 + (size_t)((((n >> 3) & 3) * 16 + m) * 8 + (n & 7));
            w3b[idx] = f2bf(acc[ct][e] + bias);
        }
    }
}

// ---- main fused attention ----
// 256 thr = 4 waves; block = 64 rows x 256 cols. Each wave owns a 64-col quarter and ALL
// 64 rows: per iter 4 B-frags are each reused by 4 A-frag MFMAs (B L2-traffic halved to
// 512 MB total). P computed cooperatively (thread (r=tid>>2, oc=tid&3): row r, 8 j's, both
// heads) into double-buffered swizzled Pt (one barrier/iter). Bitmask staged in LDS.
// Denominator: per-thread f32 accumulate + 2-lane shuffle reduce (saves 16 acc VGPRs).
__global__ __launch_bounds__(256, 4) void attn_fused(
        const unsigned int* __restrict__ abits, const float* __restrict__ s1a,
        const float* __restrict__ s2h, const unsigned short* __restrict__ w3b,
        unsigned short* __restrict__ pacc, float* __restrict__ pden)
{
    __shared__ unsigned short Pt[2][2][64][32];  // [buf][head][row][j] 16 KB, swizzled granules
    __shared__ float s2t[2][JC];                 // 8 KB
    __shared__ unsigned int abt[64][32];         // 8 KB bitmask tile

    const int tid = threadIdx.x;
    const int ln = tid & 63;
    const int m = ln & 15, kq = ln >> 4;
    const int cg = tid >> 6;                 // wave = col-quarter
    const int hw = cg >> 1;                  // head of this wave's cols
    const int r = tid >> 2, oc = tid & 3;    // P-gen: row, j-octet of 8
    const int i0 = blockIdx.x * 64;
    const int sidx = blockIdx.y;
    const int j0 = sidx * JC;
    const int sw = kq ^ ((m >> 1) & 3);

    const float s1r0 = s1a[(i0 + r) * 2 + 0];
    const float s1r1 = s1a[(i0 + r) * 2 + 1];
    // swizzled Pt write (16B granule g' = oc ^ ((r>>1)&3)); head +2048, buf +4096 (shorts)
    unsigned short* ptw = &Pt[0][0][0][0] + r * 32 + ((oc ^ ((r >> 1) & 3)) << 3);
    // swizzled Pt read base: row m (+rt*512), granule sw (rt*16 rows don't change the XOR)
    const unsigned short* pta = &Pt[0][0][0][0] + hw * 2048 + m * 32 + (sw << 3);
    const unsigned short* w3p = w3b + ((size_t)(j0 >> 5) * 16 + cg * 4) * 512 + ln * 8;

    f32x4 acc[4][4];
#pragma unroll
    for (int rt = 0; rt < 4; ++rt)
#pragma unroll
        for (int f = 0; f < 4; ++f) acc[rt][f] = (f32x4){0.f, 0.f, 0.f, 0.f};
    float d0 = 0.f, d1 = 0.f;

    // prologue: stage s2 planes + bitmask tile
    for (int x = tid; x < 2 * JC; x += 256) {
        int h = x >> 10, j = x & (JC - 1);
        s2t[h][j] = s2h[(size_t)h * NN + j0 + j];
    }
    for (int x = tid; x < 64 * 32; x += 256) {
        int rr = x >> 5, tt = x & 31;
        abt[rr][tt] = abits[(size_t)(i0 + rr) * 256 + (j0 >> 5) + tt];
    }
    __syncthreads();

    for (int t = 0; t < NT; ++t) {
        const int buf = t & 1;
        // B(t): 4 frags, each reused by 4 row-tiles (L2-resident; consumed after barrier)
        const unsigned short* bp = w3p + (size_t)t * 8192;
        short8 bf0 = *(const short8*)(bp);
        short8 bf1 = *(const short8*)(bp + 512);
        short8 bf2 = *(const short8*)(bp + 1024);
        short8 bf3 = *(const short8*)(bp + 1536);
        // ---- P-gen(t): 8 j's x 2 heads per thread ----
        {
            unsigned int bits = abt[r][t] >> (oc * 8);
            float4 sv00 = *(const float4*)&s2t[0][t * 32 + oc * 8];
            float4 sv01 = *(const float4*)&s2t[0][t * 32 + oc * 8 + 4];
            float4 sv10 = *(const float4*)&s2t[1][t * 32 + oc * 8];
            float4 sv11 = *(const float4*)&s2t[1][t * 32 + oc * 8 + 4];
            float f0[8] = {sv00.x, sv00.y, sv00.z, sv00.w, sv01.x, sv01.y, sv01.z, sv01.w};
            float f1[8] = {sv10.x, sv10.y, sv10.z, sv10.w, sv11.x, sv11.y, sv11.z, sv11.w};
            float q[8], u[8];
#pragma unroll
            for (int k = 0; k < 8; ++k) {
                float x0 = s1r0 + f0[k]; x0 = fmaxf(x0, 0.2f * x0);
                float x1 = s1r1 + f1[k]; x1 = fmaxf(x1, 0.2f * x1);
                bool on = (bits >> k) & 1u;
                q[k] = on ? fexp2(x0) : 0.f;
                u[k] = on ? fexp2(x1) : 0.f;
            }
            d0 += ((q[0] + q[1]) + (q[2] + q[3])) + ((q[4] + q[5]) + (q[6] + q[7]));
            d1 += ((u[0] + u[1]) + (u[2] + u[3])) + ((u[4] + u[5]) + (u[6] + u[7]));
            uint4 w0 = {cvtpk(q[0], q[1]), cvtpk(q[2], q[3]), cvtpk(q[4], q[5]), cvtpk(q[6], q[7])};
            uint4 w1 = {cvtpk(u[0], u[1]), cvtpk(u[2], u[3]), cvtpk(u[4], u[5]), cvtpk(u[6], u[7])};
            unsigned short* pw = ptw + buf * 4096;
            *(uint4*)pw = w0;
            *(uint4*)(pw + 2048) = w1;
        }
        asm volatile("s_waitcnt lgkmcnt(0)" ::: "memory");
        __builtin_amdgcn_sched_barrier(0);
        __builtin_amdgcn_s_barrier();
        asm volatile("" ::: "memory");
        // ---- MFMA(t): 4 A-frags x 4 B-frags ----
        {
            const unsigned short* pa = pta + buf * 4096;
            short8 a0 = *(const short8*)(pa);
            short8 a1 = *(const short8*)(pa + 512);
            short8 a2 = *(const short8*)(pa + 1024);
            short8 a3 = *(const short8*)(pa + 1536);
            __builtin_amdgcn_s_setprio(1);
            acc[0][0] = __builtin_amdgcn_mfma_f32_16x16x32_bf16(a0, bf0, acc[0][0], 0, 0, 0);
            acc[1][0] = __builtin_amdgcn_mfma_f32_16x16x32_bf16(a1, bf0, acc[1][0], 0, 0, 0);
            acc[2][0] = __builtin_amdgcn_mfma_f32_16x16x32_bf16(a2, bf0, acc[2][0], 0, 0, 0);
            acc[3][0] = __builtin_amdgcn_mfma_f32_16x16x32_bf16(a3, bf0, acc[3][0], 0, 0, 0);
            acc[0][1] = __builtin_amdgcn_mfma_f32_16x16x32_bf16(a0, bf1, acc[0][1], 0, 0, 0);
            acc[1][1] = __builtin_amdgcn_mfma_f32_16x16x32_bf16(a1, bf1, acc[1][1], 0, 0, 0);
            acc[2][1] = __builtin_amdgcn_mfma_f32_16x16x32_bf16(a2, bf1, acc[2][1], 0, 0, 0);
            acc[3][1] = __builtin_amdgcn_mfma_f32_16x16x32_bf16(a3, bf1, acc[3][1], 0, 0, 0);
            acc[0][2] = __builtin_amdgcn_mfma_f32_16x16x32_bf16(a0, bf2, acc[0][2], 0, 0, 0);
            acc[1][2] = __builtin_amdgcn_mfma_f32_16x16x32_bf16(a1, bf2, acc[1][2], 0, 0, 0);
            acc[2][2] = __builtin_amdgcn_mfma_f32_16x16x32_bf16(a2, bf2, acc[2][2], 0, 0, 0);
            acc[3][2] = __builtin_amdgcn_mfma_f32_16x16x32_bf16(a3, bf2, acc[3][2], 0, 0, 0);
            acc[0][3] = __builtin_amdgcn_mfma_f32_16x16x32_bf16(a0, bf3, acc[0][3], 0, 0, 0);
            acc[1][3] = __builtin_amdgcn_mfma_f32_16x16x32_bf16(a1, bf3, acc[1][3], 0, 0, 0);
            acc[2][3] = __builtin_amdgcn_mfma_f32_16x16x32_bf16(a2, bf3, acc[2][3], 0, 0, 0);
            acc[3][3] = __builtin_amdgcn_mfma_f32_16x16x32_bf16(a3, bf3, acc[3][3], 0, 0, 0);
            __builtin_amdgcn_s_setprio(0);
        }
    }

    // den: reduce the 4 oc-threads of each row (lane bits 0-1)
    d0 += __shfl_xor(d0, 1); d0 += __shfl_xor(d0, 2);
    d1 += __shfl_xor(d1, 1); d1 += __shfl_xor(d1, 2);
    if (oc == 0) {
        size_t base = ((size_t)sidx * NN + i0 + r) * 2;
        pden[base + 0] = d0;
        pden[base + 1] = d1;
    }
    size_t pb_ = (size_t)sidx * NN * 256;
#pragma unroll
    for (int rt = 0; rt < 4; ++rt)
#pragma unroll
        for (int e = 0; e < 4; ++e) {
            int row = i0 + rt * 16 + kq * 4 + e;
#pragma unroll
            for (int f = 0; f < 4; ++f) {
                int col = cg * 64 + f * 16 + m;
                __builtin_nontemporal_store(f2bf(acc[rt][f][e]), &pacc[pb_ + (size_t)row * 256 + col]);
            }
        }
}

// combine: 8 outputs per thread
__global__ void combine_kernel(const unsigned short* __restrict__ pacc, const float* __restrict__ pden,
                               float* __restrict__ out) {
    size_t idx = ((size_t)blockIdx.x * 256 + threadIdx.x) * 8;
    int i = (int)(idx >> 8);
    int c = (int)(idx & 255);
    int hh = c >> 7;
    float acc[8];
#pragma unroll
    for (int e = 0; e < 8; ++e) acc[e] = 0.f;
    float den = 0.f;
    for (int s = 0; s < S_SPLIT; ++s) {
        uint4 v = *(const uint4*)&pacc[(size_t)s * NN * 256 + idx];
        unsigned int uu[4] = {v.x, v.y, v.z, v.w};
#pragma unroll
        for (int q = 0; q < 4; ++q) {
            acc[2*q]   += bf2f((unsigned short)(uu[q] & 0xffff));
            acc[2*q+1] += bf2f((unsigned short)(uu[q] >> 16));
        }
        den += pden[((size_t)s * NN + i) * 2 + hh];
    }
    float r = 1.f / den;
    float4 o0 = {acc[0]*r, acc[1]*r, acc[2]*r, acc[3]*r};
    float4 o1 = {acc[4]*r, acc[5]*r, acc[6]*r, acc[7]*r};
    *(float4*)&out[idx] = o0;
    *(float4*)&out[idx + 4] = o1;
}

extern "C" void kernel_launch(void* const* d_in, const int* in_sizes, int n_in,
                              void* d_out, int out_size, void* d_ws, size_t ws_size,
                              hipStream_t stream) {
    const float* hmat = (const float*)d_in[0];
    const int*   adj  = (const int*)d_in[1];
    const float* W1   = (const float*)d_in[2];
    const float* b1   = (const float*)d_in[3];
    const float* W2   = (const float*)d_in[4];
    const float* b2   = (const float*)d_in[5];
    const float* W3   = (const float*)d_in[6];
    const float* b3   = (const float*)d_in[7];
    const float* a    = (const float*)d_in[8];
    float* out = (float*)d_out;

    char* p = (char*)d_ws;
    float* v1   = (float*)p; p += 2048;
    float* v2   = (float*)p; p += 2048;
    float* bd   = (float*)p; p += 256;
    float* s1   = (float*)p; p += (size_t)NN * 2 * sizeof(float);
    float* s2h  = (float*)p; p += (size_t)NN * 2 * sizeof(float);
    float* v1p  = (float*)p; p += 8 * 512 * sizeof(float);
    float* v2p  = (float*)p; p += 8 * 512 * sizeof(float);
    unsigned short* w3hi = (unsigned short*)p; p += 65536 * 2;
    unsigned short* w3lo = (unsigned short*)p; p += 65536 * 2;
    unsigned short* w3b  = (unsigned short*)p; p += (size_t)NN * 256 * 2;
    unsigned int* abits  = (unsigned int*)p;   p += (size_t)NN * 256 * sizeof(unsigned int);
    float* pden = (float*)p; p += (size_t)S_SPLIT * NN * 2 * sizeof(float);
    unsigned short* pacc = (unsigned short*)p;

    pack_kernel<<<(NN * 256) / 256, 256, 0, stream>>>(adj, abits);
    prep_partial<<<16, 512, 0, stream>>>(W1, W2, a, v1p, v2p);
    prep_reduce<<<1, 512, 0, stream>>>(b1, b2, a, v1p, v2p, v1, v2, bd);
    s_kernel<<<NN / 4, 256, 0, stream>>>(hmat, v1, v2, bd, s1, s2h);
    wcvt_kernel<<<256, 256, 0, stream>>>(W3, w3hi, w3lo);
    w3_kernel<<<256, 256, 0, stream>>>(hmat, w3hi, w3lo, b3, w3b);
    attn_fused<<<dim3(NN / 64, S_SPLIT), 256, 0, stream>>>(abits, s1, s2h, w3b, pacc, pden);
    combine_kernel<<<(NN * 256) / (256 * 8), 256, 0, stream>>>(pacc, pden, out);
}

// Round 11
// 151.969 us; speedup vs baseline: 1.1322x; 1.0115x over previous
//
#include <hip/hip_runtime.h>
#include <hip/hip_bf16.h>

#define NN 8192
#define LOG2E 1.44269504088896f
#define S_SPLIT 8
#define JC 1024
#define NT 32

typedef __attribute__((ext_vector_type(8))) short short8;
typedef __attribute__((ext_vector_type(4))) float f32x4;

static __device__ __forceinline__ float bf2f(unsigned short u) {
    union { unsigned int i; float f; } v; v.i = ((unsigned int)u) << 16; return v.f;
}
static __device__ __forceinline__ unsigned short f2bf(float f) {
    union { float f; unsigned int i; } v; v.f = f;
    unsigned int lsb = (v.i >> 16) & 1u;
    v.i += 0x7fffu + lsb;
    return (unsigned short)(v.i >> 16);
}
static __device__ __forceinline__ unsigned int cvtpk(float lo, float hi) {
    unsigned int r;
    asm("v_cvt_pk_bf16_f32 %0, %1, %2" : "=v"(r) : "v"(lo), "v"(hi));
    return r;
}
static __device__ __forceinline__ float fexp2(float x) { return __builtin_amdgcn_exp2f(x); }

static __device__ __forceinline__ void cvt8(const float* __restrict__ p, short8& hi, short8& lo) {
    float4 u = *(const float4*)p;
    float4 v = *(const float4*)(p + 4);
    float f[8] = {u.x, u.y, u.z, u.w, v.x, v.y, v.z, v.w};
#pragma unroll
    for (int j = 0; j < 8; ++j) {
        unsigned short hb = f2bf(f[j]);
        hi[j] = (short)hb;
        lo[j] = (short)f2bf(f[j] - bf2f(hb));
    }
}

// ---- pack adj (256 MB int32 0/1) -> bitmask (8 MB); tail blocks do W3 hi/lo cvt ----
__global__ __launch_bounds__(256) void pack_kernel(const int* __restrict__ adj,
                                                   unsigned int* __restrict__ abits,
                                                   const float* __restrict__ W3,
                                                   unsigned short* __restrict__ w3hi,
                                                   unsigned short* __restrict__ w3lo) {
    int b = blockIdx.x;
    if (b < 8192) {
        int w = b * 256 + threadIdx.x;
        const int* src = adj + (size_t)w * 32;
        unsigned int bits = 0;
#pragma unroll
        for (int k = 0; k < 8; ++k) {
            int4 v = *(const int4*)(src + k * 4);
            bits |= (unsigned int)(v.x & 1) << (k * 4 + 0);
            bits |= (unsigned int)(v.y & 1) << (k * 4 + 1);
            bits |= (unsigned int)(v.z & 1) << (k * 4 + 2);
            bits |= (unsigned int)(v.w & 1) << (k * 4 + 3);
        }
        abits[w] = bits;
    } else {
        int i = (b - 8192) * 256 + threadIdx.x;   // 65536 W3 elements
        float f = W3[i];
        unsigned short hb = f2bf(f);
        w3hi[i] = hb;
        w3lo[i] = f2bf(f - bf2f(hb));
    }
}

// ---- prep: v1/v2 (W^T a vectors), split over 16 blocks then reduced ----
__global__ void prep_partial(const float* __restrict__ W1, const float* __restrict__ W2,
                             const float* __restrict__ a,
                             float* __restrict__ v1p, float* __restrict__ v2p) {
    int b = blockIdx.x;
    int t = threadIdx.x;
    int hh = t >> 8, k = t & 255;
    int c0 = (b & 7) * 16;
    const float* W = (b < 8) ? W1 : W2;
    int aoff = (b < 8) ? 0 : 128;
    float acc = 0.f;
    for (int c = c0; c < c0 + 16; ++c)
        acc += W[(size_t)(hh * 128 + c) * 256 + k] * a[hh * 256 + aoff + c];
    ((b < 8) ? v1p : v2p)[(b & 7) * 512 + t] = acc;
}

__global__ void prep_reduce(const float* __restrict__ b1, const float* __restrict__ b2,
                            const float* __restrict__ a,
                            const float* __restrict__ v1p, const float* __restrict__ v2p,
                            float* __restrict__ v1, float* __restrict__ v2, float* __restrict__ bd) {
    int t = threadIdx.x;
    float a1 = 0.f, a2 = 0.f;
    for (int b = 0; b < 8; ++b) { a1 += v1p[b * 512 + t]; a2 += v2p[b * 512 + t]; }
    v1[t] = a1;
    v2[t] = a2;
    int g = t >> 7;
    int hh = g >> 1, which = g & 1, c = t & 127;
    float prod = which ? b2[hh * 128 + c] * a[hh * 256 + 128 + c]
                       : b1[hh * 128 + c] * a[hh * 256 + c];
#pragma unroll
    for (int off = 1; off < 64; off <<= 1) prod += __shfl_xor(prod, off);
    __shared__ float ws[8];
    if ((t & 63) == 0) ws[t >> 6] = prod;
    __syncthreads();
    if (t < 4) bd[t] = ws[2 * t] + ws[2 * t + 1];
}

// s1[n][h] interleaved; s2 per-head planes s2h[h][n]. Both pre-scaled by log2(e).
__global__ __launch_bounds__(256) void s_kernel(const float* __restrict__ hmat,
                         const float* __restrict__ v1, const float* __restrict__ v2,
                         const float* __restrict__ bd,
                         float* __restrict__ s1o, float* __restrict__ s2o) {
    int w = threadIdx.x >> 6, l = threadIdx.x & 63;
    int n = blockIdx.x * 4 + w;
    float4 hv  = *(const float4*)(hmat + (size_t)n * 256 + l * 4);
    float4 va0 = *(const float4*)(v1 + l * 4);
    float4 va1 = *(const float4*)(v1 + 256 + l * 4);
    float4 vb0 = *(const float4*)(v2 + l * 4);
    float4 vb1 = *(const float4*)(v2 + 256 + l * 4);
    float s10 = hv.x*va0.x + hv.y*va0.y + hv.z*va0.z + hv.w*va0.w;
    float s11 = hv.x*va1.x + hv.y*va1.y + hv.z*va1.z + hv.w*va1.w;
    float s20 = hv.x*vb0.x + hv.y*vb0.y + hv.z*vb0.z + hv.w*vb0.w;
    float s21 = hv.x*vb1.x + hv.y*vb1.y + hv.z*vb1.z + hv.w*vb1.w;
#pragma unroll
    for (int off = 1; off < 64; off <<= 1) {
        s10 += __shfl_xor(s10, off);
        s11 += __shfl_xor(s11, off);
        s20 += __shfl_xor(s20, off);
        s21 += __shfl_xor(s21, off);
    }
    if (l == 0) {
        s1o[n*2 + 0] = (s10 + bd[0]) * LOG2E;
        s1o[n*2 + 1] = (s11 + bd[2]) * LOG2E;
        s2o[n]       = (s20 + bd[1]) * LOG2E;
        s2o[NN + n]  = (s21 + bd[3]) * LOG2E;
    }
}

// W3h in MFMA-fragment-major layout (w3b), split-bf16 3-MFMA.
__global__ __launch_bounds__(256) void w3_kernel(const float* __restrict__ hmat,
                                                 const unsigned short* __restrict__ w3hi,
                                                 const unsigned short* __restrict__ w3lo,
                                                 const float* __restrict__ b3,
                                                 unsigned short* __restrict__ w3b) {
    int tid = threadIdx.x;
    int w = tid >> 6, l = tid & 63;
    int m = l & 15, kq = l >> 4;
    int n0 = (blockIdx.x * 2 + (w & 1)) * 16;
    int c0 = (w >> 1) * 8;
    f32x4 acc[8];
#pragma unroll
    for (int ct = 0; ct < 8; ++ct) acc[ct] = (f32x4){0.f, 0.f, 0.f, 0.f};
    for (int k0 = 0; k0 < 256; k0 += 32) {
        short8 ahi, alo;
        cvt8(hmat + (size_t)(n0 + m) * 256 + k0 + kq * 8, ahi, alo);
#pragma unroll
        for (int ct = 0; ct < 8; ++ct) {
            int c = (c0 + ct) * 16 + m;
            short8 bhi = *(const short8*)&w3hi[(size_t)c * 256 + k0 + kq * 8];
            short8 blo = *(const short8*)&w3lo[(size_t)c * 256 + k0 + kq * 8];
            acc[ct] = __builtin_amdgcn_mfma_f32_16x16x32_bf16(ahi, bhi, acc[ct], 0, 0, 0);
            acc[ct] = __builtin_amdgcn_mfma_f32_16x16x32_bf16(alo, bhi, acc[ct], 0, 0, 0);
            acc[ct] = __builtin_amdgcn_mfma_f32_16x16x32_bf16(ahi, blo, acc[ct], 0, 0, 0);
        }
    }
#pragma unroll
    for (int ct = 0; ct < 8; ++ct) {
        int c = (c0 + ct) * 16 + m;
        float bias = b3[c];
#pragma unroll
        for (int e = 0; e < 4; ++e) {
            int n = n0 + kq * 4 + e;
            size_t idx = ((size_t)(n >> 5) * 16 + (c >> 4)) * 512 + (size_t)((((n >> 3) & 3) * 16 + m) * 8 + (n & 7));
            w3b[idx] = f2bf(acc[ct][e] + bias);
        }
    }
}

// ---- main fused attention (round-10 structure, register-dieted) ----
// 256 thr = 4 waves; block = 64 rows x 256 cols; wave cg owns a 64-col quarter, all 64 rows:
// per iter 4 B-frags each reused by 4 A-frag MFMAs. A-frags consumed SEQUENTIALLY (1 live,
// 8 VGPR, vs 4/32 before); P-gen in two quads. Peak VGPR ~110 < 128 cap => no scratch spill.
__global__ __launch_bounds__(256, 4) void attn_fused(
        const unsigned int* __restrict__ abits, const float* __restrict__ s1a,
        const float* __restrict__ s2h, const unsigned short* __restrict__ w3b,
        unsigned short* __restrict__ pacc, float* __restrict__ pden)
{
    __shared__ unsigned short Pt[2][2][64][32];  // [buf][head][row][j] 16 KB, swizzled granules
    __shared__ float s2t[2][JC];                 // 8 KB
    __shared__ unsigned int abt[64][32];         // 8 KB

    const int tid = threadIdx.x;
    const int ln = tid & 63;
    const int m = ln & 15, kq = ln >> 4;
    const int cg = tid >> 6;
    const int hw = cg >> 1;
    const int r = tid >> 2, oc = tid & 3;
    const int i0 = blockIdx.x * 64;
    const int sidx = blockIdx.y;
    const int j0 = sidx * JC;
    const int sw = kq ^ ((m >> 1) & 3);

    const float s1r0 = s1a[(i0 + r) * 2 + 0];
    const float s1r1 = s1a[(i0 + r) * 2 + 1];
    unsigned short* ptw = &Pt[0][0][0][0] + r * 32 + ((oc ^ ((r >> 1) & 3)) << 3);
    const unsigned short* pta = &Pt[0][0][0][0] + hw * 2048 + m * 32 + (sw << 3);
    const unsigned short* w3p = w3b + ((size_t)(j0 >> 5) * 16 + cg * 4) * 512 + ln * 8;

    f32x4 acc[4][4];
#pragma unroll
    for (int rt = 0; rt < 4; ++rt)
#pragma unroll
        for (int f = 0; f < 4; ++f) acc[rt][f] = (f32x4){0.f, 0.f, 0.f, 0.f};
    float d0 = 0.f, d1 = 0.f;

    for (int x = tid; x < 2 * JC; x += 256) {
        int h = x >> 10, j = x & (JC - 1);
        s2t[h][j] = s2h[(size_t)h * NN + j0 + j];
    }
    for (int x = tid; x < 64 * 32; x += 256) {
        int rr = x >> 5, tt = x & 31;
        abt[rr][tt] = abits[(size_t)(i0 + rr) * 256 + (j0 >> 5) + tt];
    }
    __syncthreads();

    for (int t = 0; t < NT; ++t) {
        const int buf = t & 1;
        // B(t): issued first, L2-resident, consumed after the barrier
        const unsigned short* bp = w3p + (size_t)t * 8192;
        short8 bf0 = *(const short8*)(bp);
        short8 bf1 = *(const short8*)(bp + 512);
        short8 bf2 = *(const short8*)(bp + 1024);
        short8 bf3 = *(const short8*)(bp + 1536);
        // ---- P-gen(t), two quads to cap live registers ----
        {
            unsigned int bits = abt[r][t] >> (oc * 8);
            uint4 w0, w1;
            {
                float4 sv0 = *(const float4*)&s2t[0][t * 32 + oc * 8];
                float4 sv1 = *(const float4*)&s2t[1][t * 32 + oc * 8];
                float x0, q0, q1, q2, q3, u0, u1, u2, u3;
                x0 = s1r0 + sv0.x; x0 = fmaxf(x0, 0.2f * x0); q0 = (bits & 1u) ? fexp2(x0) : 0.f;
                x0 = s1r0 + sv0.y; x0 = fmaxf(x0, 0.2f * x0); q1 = (bits & 2u) ? fexp2(x0) : 0.f;
                x0 = s1r0 + sv0.z; x0 = fmaxf(x0, 0.2f * x0); q2 = (bits & 4u) ? fexp2(x0) : 0.f;
                x0 = s1r0 + sv0.w; x0 = fmaxf(x0, 0.2f * x0); q3 = (bits & 8u) ? fexp2(x0) : 0.f;
                x0 = s1r1 + sv1.x; x0 = fmaxf(x0, 0.2f * x0); u0 = (bits & 1u) ? fexp2(x0) : 0.f;
                x0 = s1r1 + sv1.y; x0 = fmaxf(x0, 0.2f * x0); u1 = (bits & 2u) ? fexp2(x0) : 0.f;
                x0 = s1r1 + sv1.z; x0 = fmaxf(x0, 0.2f * x0); u2 = (bits & 4u) ? fexp2(x0) : 0.f;
                x0 = s1r1 + sv1.w; x0 = fmaxf(x0, 0.2f * x0); u3 = (bits & 8u) ? fexp2(x0) : 0.f;
                d0 += (q0 + q1) + (q2 + q3);
                d1 += (u0 + u1) + (u2 + u3);
                w0.x = cvtpk(q0, q1); w0.y = cvtpk(q2, q3);
                w1.x = cvtpk(u0, u1); w1.y = cvtpk(u2, u3);
            }
            {
                float4 sv0 = *(const float4*)&s2t[0][t * 32 + oc * 8 + 4];
                float4 sv1 = *(const float4*)&s2t[1][t * 32 + oc * 8 + 4];
                float x0, q0, q1, q2, q3, u0, u1, u2, u3;
                x0 = s1r0 + sv0.x; x0 = fmaxf(x0, 0.2f * x0); q0 = (bits & 16u)  ? fexp2(x0) : 0.f;
                x0 = s1r0 + sv0.y; x0 = fmaxf(x0, 0.2f * x0); q1 = (bits & 32u)  ? fexp2(x0) : 0.f;
                x0 = s1r0 + sv0.z; x0 = fmaxf(x0, 0.2f * x0); q2 = (bits & 64u)  ? fexp2(x0) : 0.f;
                x0 = s1r0 + sv0.w; x0 = fmaxf(x0, 0.2f * x0); q3 = (bits & 128u) ? fexp2(x0) : 0.f;
                x0 = s1r1 + sv1.x; x0 = fmaxf(x0, 0.2f * x0); u0 = (bits & 16u)  ? fexp2(x0) : 0.f;
                x0 = s1r1 + sv1.y; x0 = fmaxf(x0, 0.2f * x0); u1 = (bits & 32u)  ? fexp2(x0) : 0.f;
                x0 = s1r1 + sv1.z; x0 = fmaxf(x0, 0.2f * x0); u2 = (bits & 64u)  ? fexp2(x0) : 0.f;
                x0 = s1r1 + sv1.w; x0 = fmaxf(x0, 0.2f * x0); u3 = (bits & 128u) ? fexp2(x0) : 0.f;
                d0 += (q0 + q1) + (q2 + q3);
                d1 += (u0 + u1) + (u2 + u3);
                w0.z = cvtpk(q0, q1); w0.w = cvtpk(q2, q3);
                w1.z = cvtpk(u0, u1); w1.w = cvtpk(u2, u3);
            }
            unsigned short* pw = ptw + buf * 4096;
            *(uint4*)pw = w0;
            *(uint4*)(pw + 2048) = w1;
        }
        asm volatile("s_waitcnt lgkmcnt(0)" ::: "memory");
        __builtin_amdgcn_sched_barrier(0);
        __builtin_amdgcn_s_barrier();
        asm volatile("" ::: "memory");
        // ---- MFMA(t): sequential A-frags (1 live), 4 B-frags resident ----
        {
            const unsigned short* pa = pta + buf * 4096;
            __builtin_amdgcn_s_setprio(1);
#pragma unroll
            for (int rt = 0; rt < 4; ++rt) {
                short8 a = *(const short8*)(pa + rt * 512);
                acc[rt][0] = __builtin_amdgcn_mfma_f32_16x16x32_bf16(a, bf0, acc[rt][0], 0, 0, 0);
                acc[rt][1] = __builtin_amdgcn_mfma_f32_16x16x32_bf16(a, bf1, acc[rt][1], 0, 0, 0);
                acc[rt][2] = __builtin_amdgcn_mfma_f32_16x16x32_bf16(a, bf2, acc[rt][2], 0, 0, 0);
                acc[rt][3] = __builtin_amdgcn_mfma_f32_16x16x32_bf16(a, bf3, acc[rt][3], 0, 0, 0);
            }
            __builtin_amdgcn_s_setprio(0);
        }
    }

    d0 += __shfl_xor(d0, 1); d0 += __shfl_xor(d0, 2);
    d1 += __shfl_xor(d1, 1); d1 += __shfl_xor(d1, 2);
    if (oc == 0) {
        size_t base = ((size_t)sidx * NN + i0 + r) * 2;
        pden[base + 0] = d0;
        pden[base + 1] = d1;
    }
    size_t pb_ = (size_t)sidx * NN * 256;
#pragma unroll
    for (int rt = 0; rt < 4; ++rt)
#pragma unroll
        for (int e = 0; e < 4; ++e) {
            int row = i0 + rt * 16 + kq * 4 + e;
#pragma unroll
            for (int f = 0; f < 4; ++f) {
                int col = cg * 64 + f * 16 + m;
                __builtin_nontemporal_store(f2bf(acc[rt][f][e]), &pacc[pb_ + (size_t)row * 256 + col]);
            }
        }
}

// combine: 8 outputs per thread
__global__ void combine_kernel(const unsigned short* __restrict__ pacc, const float* __restrict__ pden,
                               float* __restrict__ out) {
    size_t idx = ((size_t)blockIdx.x * 256 + threadIdx.x) * 8;
    int i = (int)(idx >> 8);
    int c = (int)(idx & 255);
    int hh = c >> 7;
    float acc[8];
#pragma unroll
    for (int e = 0; e < 8; ++e) acc[e] = 0.f;
    float den = 0.f;
    for (int s = 0; s < S_SPLIT; ++s) {
        uint4 v = *(const uint4*)&pacc[(size_t)s * NN * 256 + idx];
        unsigned int uu[4] = {v.x, v.y, v.z, v.w};
#pragma unroll
        for (int q = 0; q < 4; ++q) {
            acc[2*q]   += bf2f((unsigned short)(uu[q] & 0xffff));
            acc[2*q+1] += bf2f((unsigned short)(uu[q] >> 16));
        }
        den += pden[((size_t)s * NN + i) * 2 + hh];
    }
    float r = 1.f / den;
    float4 o0 = {acc[0]*r, acc[1]*r, acc[2]*r, acc[3]*r};
    float4 o1 = {acc[4]*r, acc[5]*r, acc[6]*r, acc[7]*r};
    *(float4*)&out[idx] = o0;
    *(float4*)&out[idx + 4] = o1;
}

extern "C" void kernel_launch(void* const* d_in, const int* in_sizes, int n_in,
                              void* d_out, int out_size, void* d_ws, size_t ws_size,
                              hipStream_t stream) {
    const float* hmat = (const float*)d_in[0];
    const int*   adj  = (const int*)d_in[1];
    const float* W1   = (const float*)d_in[2];
    const float* b1   = (const float*)d_in[3];
    const float* W2   = (const float*)d_in[4];
    const float* b2   = (const float*)d_in[5];
    const float* W3   = (const float*)d_in[6];
    const float* b3   = (const float*)d_in[7];
    const float* a    = (const float*)d_in[8];
    float* out = (float*)d_out;

    char* p = (char*)d_ws;
    float* v1   = (float*)p; p += 2048;
    float* v2   = (float*)p; p += 2048;
    float* bd   = (float*)p; p += 256;
    float* s1   = (float*)p; p += (size_t)NN * 2 * sizeof(float);
    float* s2h  = (float*)p; p += (size_t)NN * 2 * sizeof(float);
    float* v1p  = (float*)p; p += 8 * 512 * sizeof(float);
    float* v2p  = (float*)p; p += 8 * 512 * sizeof(float);
    unsigned short* w3hi = (unsigned short*)p; p += 65536 * 2;
    unsigned short* w3lo = (unsigned short*)p; p += 65536 * 2;
    unsigned short* w3b  = (unsigned short*)p; p += (size_t)NN * 256 * 2;
    unsigned int* abits  = (unsigned int*)p;   p += (size_t)NN * 256 * sizeof(unsigned int);
    float* pden = (float*)p; p += (size_t)S_SPLIT * NN * 2 * sizeof(float);
    unsigned short* pacc = (unsigned short*)p;

    pack_kernel<<<8192 + 256, 256, 0, stream>>>(adj, abits, W3, w3hi, w3lo);
    prep_partial<<<16, 512, 0, stream>>>(W1, W2, a, v1p, v2p);
    prep_reduce<<<1, 512, 0, stream>>>(b1, b2, a, v1p, v2p, v1, v2, bd);
    s_kernel<<<NN / 4, 256, 0, stream>>>(hmat, v1, v2, bd, s1, s2h);
    w3_kernel<<<256, 256, 0, stream>>>(hmat, w3hi, w3lo, b3, w3b);
    attn_fused<<<dim3(NN / 64, S_SPLIT), 256, 0, stream>>>(abits, s1, s2h, w3b, pacc, pden);
    combine_kernel<<<(NN * 256) / (256 * 8), 256, 0, stream>>>(pacc, pden, out);
}